// Round 1
// baseline (400.064 us; speedup 1.0000x reference)
//
#include <hip/hip_runtime.h>

#define GLOBAL_AS __attribute__((address_space(1)))
#define LDS_AS    __attribute__((address_space(3)))

typedef __bf16 bf16x8 __attribute__((ext_vector_type(8)));
typedef float  f32x4  __attribute__((ext_vector_type(4)));

// Problem dims (fixed by the reference)
constexpr int SRC_STRIDE = 8192 * 80;         // floats per batch row: 655360
constexpr int TOUT       = 2728;              // output time steps
constexpr int KDIM       = 640;
constexpr int NDIM       = 1024;
constexpr long OUT_ELEMS = (long)TOUT * 16 * 1024;  // 44695552
constexpr int SRC_ELEMS  = 32 * SRC_STRIDE;   // 20971520
constexpr int W_ELEMS    = 1024 * 640;        // 655360

__device__ __forceinline__ unsigned short f2bf(float f) {
    union { float f; unsigned u; } a; a.f = f;
    unsigned r = a.u + 0x7FFF + ((a.u >> 16) & 1);   // round-to-nearest-even
    return (unsigned short)(r >> 16);
}

// fp32 -> bf16 conversion, 4 elements/thread
__global__ void cvt_kernel(const float* __restrict__ in, unsigned short* __restrict__ out, int n4) {
    int i = blockIdx.x * blockDim.x + threadIdx.x;
    if (i >= n4) return;
    float4 v = ((const float4*)in)[i];
    ushort4 o;
    o.x = f2bf(v.x); o.y = f2bf(v.y); o.z = f2bf(v.z); o.w = f2bf(v.w);
    ((ushort4*)out)[i] = o;
}

// out_lengths = src_lengths // 3 - 2, written as fp32 after the main output
__global__ void lengths_kernel(const int* __restrict__ len, float* __restrict__ out) {
    int i = threadIdx.x;
    if (i < 32) out[OUT_ELEMS + i] = (float)(len[i] / 3 - 2);
}

// Fused GEMM (M=87296, N=1024, K=640) + bias + GLU epilogue.
// A[m][k] = srcb[(m%32)*655360 + (m/32)*240 + k]  (bf16, contiguous rows)
// B[n][k] = wb[n*640 + k]                          (bf16, N x K row-major)
// out[(t*16+b)*1024+n] = y[t*32+b][n] * sigmoid(y[t*32+b+16][n])
__global__ void glu_gemm(const __bf16* __restrict__ A,
                         const __bf16* __restrict__ Wb,
                         const float* __restrict__ bias,
                         float* __restrict__ out) {
    __shared__ __bf16 lA[128 * 64];   // 16 KB, rows of 64 bf16, chunk-swizzled
    __shared__ __bf16 lB[128 * 64];   // 16 KB

    const int tid  = threadIdx.x;
    const int lane = tid & 63;
    const int w    = tid >> 6;        // wave 0..3
    const int wm   = w & 1;           // wave M position (2x2 wave grid)
    const int wn   = w >> 1;

    const int bid = blockIdx.x;
    const int bn  = bid & 7;          // 8 N-blocks adjacent -> A-tile LLC reuse
    const int bm  = bid >> 3;         // 0..681

    // ---- staging address setup (global_load_lds: wave-uniform LDS base + lane*16B) ----
    // issue j covers rows w*32 + j*8 .. +7; lane -> row (lane>>3), physical chunk (lane&7)
    // swizzle: physical chunk p holds logical chunk c = p ^ (row&7)
    const int c8 = (((lane & 7) ^ (lane >> 3)) * 8);   // logical chunk start (elements)
    int aoff_g[4], boff_g[4];
#pragma unroll
    for (int j = 0; j < 4; ++j) {
        int r = w * 32 + j * 8 + (lane >> 3);
        int m = bm * 128 + r;
        int t = m >> 5, b = m & 31;
        aoff_g[j] = b * SRC_STRIDE + t * 240 + c8;
        int n = bn * 128 + r;
        boff_g[j] = n * 640 + c8;
    }

    // ---- fragment read offsets ----
    const int q    = lane >> 4;                        // quad 0..3
    const int poff = ((q ^ (lane & 7)) * 8);           // ks=0 physical chunk * 8 elems
    int aoff_l[4], boff_l[4];
#pragma unroll
    for (int i = 0; i < 4; ++i) {
        aoff_l[i] = (wm * 64 + i * 16 + (lane & 15)) * 64;
        boff_l[i] = (wn * 64 + i * 16 + (lane & 15)) * 64;
    }

    f32x4 acc[4][4] = {};

    for (int kb = 0; kb < 10; ++kb) {
        const int k0 = kb * 64;
#pragma unroll
        for (int j = 0; j < 4; ++j) {
            __builtin_amdgcn_global_load_lds(
                (const GLOBAL_AS void*)(A + (aoff_g[j] + k0)),
                (LDS_AS void*)(lA + (w * 32 + j * 8) * 64), 16, 0, 0);
            __builtin_amdgcn_global_load_lds(
                (const GLOBAL_AS void*)(Wb + (boff_g[j] + k0)),
                (LDS_AS void*)(lB + (w * 32 + j * 8) * 64), 16, 0, 0);
        }
        __syncthreads();
#pragma unroll
        for (int ks = 0; ks < 2; ++ks) {
            const int po = poff ^ (ks << 5);           // (p0 ^ 4)*8 == p0*8 ^ 32
            bf16x8 af[4], bfv[4];
#pragma unroll
            for (int i = 0; i < 4; ++i)
                af[i] = *(const bf16x8*)(lA + aoff_l[i] + po);
#pragma unroll
            for (int i = 0; i < 4; ++i)
                bfv[i] = *(const bf16x8*)(lB + boff_l[i] + po);
#pragma unroll
            for (int mt = 0; mt < 4; ++mt)
#pragma unroll
                for (int nt = 0; nt < 4; ++nt)
                    acc[mt][nt] = __builtin_amdgcn_mfma_f32_16x16x32_bf16(
                        af[mt], bfv[nt], acc[mt][nt], 0, 0, 0);
        }
        __syncthreads();
    }

    // ---- epilogue: bias + GLU (value row m pairs with gate row m+16; same lane/reg) ----
    const int col = lane & 15;
    float bv[4];
#pragma unroll
    for (int nt = 0; nt < 4; ++nt)
        bv[nt] = bias[bn * 128 + wn * 64 + nt * 16 + col];

    const int t_base = bm * 4 + wm * 2;
#pragma unroll
    for (int pr = 0; pr < 2; ++pr) {                   // two t-groups per wave tile
        const int t = t_base + pr;
#pragma unroll
        for (int nt = 0; nt < 4; ++nt) {
            const int n = bn * 128 + wn * 64 + nt * 16 + col;
#pragma unroll
            for (int r2 = 0; r2 < 4; ++r2) {
                const int brow = q * 4 + r2;           // b in 0..15 (value rows)
                float v = acc[pr * 2 + 0][nt][r2] + bv[nt];
                float g = acc[pr * 2 + 1][nt][r2] + bv[nt];
                float s = 1.0f / (1.0f + __expf(-g));
                out[((long)(t * 16 + brow)) * 1024 + n] = v * s;
            }
        }
    }
}

extern "C" void kernel_launch(void* const* d_in, const int* in_sizes, int n_in,
                              void* d_out, int out_size, void* d_ws, size_t ws_size,
                              hipStream_t stream) {
    const float* src  = (const float*)d_in[0];
    const int*   lens = (const int*)d_in[1];
    const float* Wf   = (const float*)d_in[2];
    const float* bias = (const float*)d_in[3];
    float* out = (float*)d_out;

    unsigned short* srcb = (unsigned short*)d_ws;          // 20971520 bf16 = 41.9 MB
    unsigned short* wb   = srcb + SRC_ELEMS;               // 655360 bf16 = 1.3 MB

    // bf16 pre-pass (src + W)
    cvt_kernel<<<SRC_ELEMS / 4 / 256, 256, 0, stream>>>(src, srcb, SRC_ELEMS / 4);
    cvt_kernel<<<W_ELEMS / 4 / 256, 256, 0, stream>>>(Wf, wb, W_ELEMS / 4);

    // out_lengths
    lengths_kernel<<<1, 64, 0, stream>>>(lens, out);

    // fused GEMM + GLU: grid = (M/128) * (N/128) = 682 * 8
    glu_gemm<<<682 * 8, 256, 0, stream>>>((const __bf16*)srcb, (const __bf16*)wb, bias, out);
}

// Round 2
// 349.218 us; speedup vs baseline: 1.1456x; 1.1456x over previous
//
#include <hip/hip_runtime.h>

#define GLOBAL_AS __attribute__((address_space(1)))
#define LDS_AS    __attribute__((address_space(3)))

typedef __bf16 bf16x8 __attribute__((ext_vector_type(8)));
typedef float  f32x4  __attribute__((ext_vector_type(4)));

// Problem dims (fixed by the reference)
constexpr int SRC_STRIDE = 8192 * 80;         // floats per batch row: 655360
constexpr int TOUT       = 2728;              // output time steps
constexpr long OUT_ELEMS = (long)TOUT * 16 * 1024;  // 44695552
constexpr int SRC_ELEMS  = 32 * SRC_STRIDE;   // 20971520
constexpr int W_ELEMS    = 1024 * 640;        // 655360
constexpr int MBLK       = 682;               // ceil(87296/128)

__device__ __forceinline__ unsigned short f2bf(float f) {
    union { float f; unsigned u; } a; a.f = f;
    unsigned r = a.u + 0x7FFF + ((a.u >> 16) & 1);   // round-to-nearest-even
    return (unsigned short)(r >> 16);
}

// fp32 -> bf16 conversion, 4 elements/thread
__global__ void cvt_kernel(const float* __restrict__ in, unsigned short* __restrict__ out, int n4) {
    int i = blockIdx.x * blockDim.x + threadIdx.x;
    if (i >= n4) return;
    float4 v = ((const float4*)in)[i];
    ushort4 o;
    o.x = f2bf(v.x); o.y = f2bf(v.y); o.z = f2bf(v.z); o.w = f2bf(v.w);
    ((ushort4*)out)[i] = o;
}

// out_lengths = src_lengths // 3 - 2, written as fp32 after the main output
__global__ void lengths_kernel(const int* __restrict__ len, float* __restrict__ out) {
    int i = threadIdx.x;
    if (i < 32) out[OUT_ELEMS + i] = (float)(len[i] / 3 - 2);
}

// Fused GEMM (M=87296, N=1024, K=640) + bias + GLU epilogue.
// A[m][k] = srcb[(m%32)*655360 + (m/32)*240 + k]  (bf16, contiguous rows)
// B[n][k] = wb[n*640 + k]                          (bf16, N x K row-major)
// out[(t*16+b)*1024+n] = y[t*32+b][n] * sigmoid(y[t*32+b+16][n])
__global__ void glu_gemm(const __bf16* __restrict__ A,
                         const __bf16* __restrict__ Wb,
                         const float* __restrict__ bias,
                         float* __restrict__ out) {
    __shared__ __bf16 lA[128 * 64];   // 16 KB, rows of 64 bf16, chunk-swizzled
    __shared__ __bf16 lB[128 * 64];   // 16 KB

    const int tid  = threadIdx.x;
    const int lane = tid & 63;
    const int w    = tid >> 6;        // wave 0..3
    const int wm   = w & 1;           // wave M position (2x2 wave grid)
    const int wn   = w >> 1;

    // XCD-aware swizzle: blocks are distributed round-robin over the 8 XCDs by
    // bid%8. Give all 8 bn-siblings (which share one A-tile) the same bid%8 so
    // they land on ONE XCD's L2, consecutively numbered (temporal locality).
    // bid = grp*64 + bn*8 + bm_local  ->  bid%8 == bm_local for all bn.
    const int bid = blockIdx.x;
    const int bn  = (bid >> 3) & 7;
    const int bm  = (bid >> 6) * 8 + (bid & 7);
    if (bm >= MBLK) return;           // tail of last partial group (48 idle blocks)

    // ---- staging address setup (global_load_lds: wave-uniform LDS base + lane*16B) ----
    // issue j covers rows w*32 + j*8 .. +7; lane -> row (lane>>3), physical chunk (lane&7)
    // swizzle: physical chunk p holds logical chunk c = p ^ (row&7)
    const int c8 = (((lane & 7) ^ (lane >> 3)) * 8);   // logical chunk start (elements)
    int aoff_g[4], boff_g[4];
#pragma unroll
    for (int j = 0; j < 4; ++j) {
        int r = w * 32 + j * 8 + (lane >> 3);
        int m = bm * 128 + r;
        int t = m >> 5, b = m & 31;
        aoff_g[j] = b * SRC_STRIDE + t * 240 + c8;
        int n = bn * 128 + r;
        boff_g[j] = n * 640 + c8;
    }

    // ---- fragment read offsets ----
    const int q    = lane >> 4;                        // quad 0..3
    const int poff = ((q ^ (lane & 7)) * 8);           // ks=0 physical chunk * 8 elems
    int aoff_l[4], boff_l[4];
#pragma unroll
    for (int i = 0; i < 4; ++i) {
        aoff_l[i] = (wm * 64 + i * 16 + (lane & 15)) * 64;
        boff_l[i] = (wn * 64 + i * 16 + (lane & 15)) * 64;
    }

    f32x4 acc[4][4] = {};

    for (int kb = 0; kb < 10; ++kb) {
        const int k0 = kb * 64;
#pragma unroll
        for (int j = 0; j < 4; ++j) {
            __builtin_amdgcn_global_load_lds(
                (const GLOBAL_AS void*)(A + (aoff_g[j] + k0)),
                (LDS_AS void*)(lA + (w * 32 + j * 8) * 64), 16, 0, 0);
            __builtin_amdgcn_global_load_lds(
                (const GLOBAL_AS void*)(Wb + (boff_g[j] + k0)),
                (LDS_AS void*)(lB + (w * 32 + j * 8) * 64), 16, 0, 0);
        }
        __syncthreads();
#pragma unroll
        for (int ks = 0; ks < 2; ++ks) {
            const int po = poff ^ (ks << 5);           // (p0 ^ 4)*8 == p0*8 ^ 32
            bf16x8 af[4], bfv[4];
#pragma unroll
            for (int i = 0; i < 4; ++i)
                af[i] = *(const bf16x8*)(lA + aoff_l[i] + po);
#pragma unroll
            for (int i = 0; i < 4; ++i)
                bfv[i] = *(const bf16x8*)(lB + boff_l[i] + po);
#pragma unroll
            for (int mt = 0; mt < 4; ++mt)
#pragma unroll
                for (int nt = 0; nt < 4; ++nt)
                    acc[mt][nt] = __builtin_amdgcn_mfma_f32_16x16x32_bf16(
                        af[mt], bfv[nt], acc[mt][nt], 0, 0, 0);
        }
        __syncthreads();
    }

    // ---- epilogue: bias + GLU (value row m pairs with gate row m+16; same lane/reg) ----
    const int col = lane & 15;
    float bv[4];
#pragma unroll
    for (int nt = 0; nt < 4; ++nt)
        bv[nt] = bias[bn * 128 + wn * 64 + nt * 16 + col];

    const int t_base = bm * 4 + wm * 2;
#pragma unroll
    for (int pr = 0; pr < 2; ++pr) {                   // two t-groups per wave tile
        const int t = t_base + pr;
#pragma unroll
        for (int nt = 0; nt < 4; ++nt) {
            const int n = bn * 128 + wn * 64 + nt * 16 + col;
#pragma unroll
            for (int r2 = 0; r2 < 4; ++r2) {
                const int brow = q * 4 + r2;           // b in 0..15 (value rows)
                float v = acc[pr * 2 + 0][nt][r2] + bv[nt];
                float g = acc[pr * 2 + 1][nt][r2] + bv[nt];
                float s = 1.0f / (1.0f + __expf(-g));
                out[((long)(t * 16 + brow)) * 1024 + n] = v * s;
            }
        }
    }
}

extern "C" void kernel_launch(void* const* d_in, const int* in_sizes, int n_in,
                              void* d_out, int out_size, void* d_ws, size_t ws_size,
                              hipStream_t stream) {
    const float* src  = (const float*)d_in[0];
    const int*   lens = (const int*)d_in[1];
    const float* Wf   = (const float*)d_in[2];
    const float* bias = (const float*)d_in[3];
    float* out = (float*)d_out;

    unsigned short* srcb = (unsigned short*)d_ws;          // 20971520 bf16 = 41.9 MB
    unsigned short* wb   = srcb + SRC_ELEMS;               // 655360 bf16 = 1.3 MB

    // bf16 pre-pass (src + W)
    cvt_kernel<<<SRC_ELEMS / 4 / 256, 256, 0, stream>>>(src, srcb, SRC_ELEMS / 4);
    cvt_kernel<<<W_ELEMS / 4 / 256, 256, 0, stream>>>(Wf, wb, W_ELEMS / 4);

    // out_lengths
    lengths_kernel<<<1, 64, 0, stream>>>(lens, out);

    // fused GEMM + GLU: 86 groups x (8 bn x 8 bm_local) = 5504 blocks (48 idle tail)
    glu_gemm<<<86 * 64, 256, 0, stream>>>((const __bf16*)srcb, (const __bf16*)wb, bias, out);
}